// Round 5
// baseline (123.435 us; speedup 1.0000x reference)
//
#include <hip/hip_runtime.h>

// Problem sizes
#define LN   512      // FFT length
#define FB   257      // rfft bins = L/2+1
#define CB   128      // channels
#define NROW 2048     // B*C rows
#define GC   8        // g-chunks in k_dist (7x32 + 1x33)

// ---------------------------------------------------------------------------
// Kernel 0: prep — At_d[f][g] = (double)A[g][f] (blocks 0..258) +
//           twiddles tw[j] = exp(-2*pi*i*j/512) (block 259).
// ---------------------------------------------------------------------------
__global__ void k_prep(const float* __restrict__ A, double* __restrict__ At_d,
                       double2* __restrict__ tw) {
    if (blockIdx.x < 259) {
        int idx = blockIdx.x * 256 + threadIdx.x;
        if (idx < FB * FB) {
            int f = idx / FB;
            int g = idx - f * FB;
            At_d[idx] = (double)A[g * FB + f];
        }
    } else {
        int j = threadIdx.x;  // 0..255
        const double PI = 3.14159265358979323846264338327950288;
        double theta = -2.0 * PI * (double)j / 512.0;
        double s, c;
        sincos(theta, &s, &c);
        tw[j] = make_double2(c, s);
    }
}

// ---------------------------------------------------------------------------
// Kernel 1: paired real FFT — one complex-512 FFT per TWO input rows
// (x_r0 + i*x_r1), radix-2 DIT in LDS, unpack both magnitudes.
// Output TRANSPOSED: xft[f][row] (so zmat can scalar-load row groups).
// 1024 blocks x 128 threads.
// ---------------------------------------------------------------------------
__global__ __launch_bounds__(128)
void k_fft2(const float* __restrict__ x,
            const double2* __restrict__ twg,
            double* __restrict__ xft) {
    __shared__ double2 a[LN];
    __shared__ double2 tw[256];
    const int pair = blockIdx.x;          // 0..1023
    const int tid  = threadIdx.x;         // 0..127
    const int r0   = pair * 2;

    for (int t = tid; t < 256; t += 128) tw[t] = twg[t];

    const float* x0 = x + (size_t)r0 * LN;
    const float* x1 = x0 + LN;
    #pragma unroll
    for (int q = 0; q < 4; ++q) {
        int n = tid + 128 * q;
        int r = (int)(__brev((unsigned)n) >> 23);  // 9-bit reverse
        a[r] = make_double2((double)x0[n], (double)x1[n]);
    }
    __syncthreads();

    for (int s = 1; s <= 9; ++s) {
        const int half   = 1 << (s - 1);
        const int tshift = 9 - s;
        #pragma unroll
        for (int u = 0; u < 2; ++u) {
            int t   = tid + 128 * u;
            int k   = t & (half - 1);
            int grp = t >> (s - 1);
            int p0  = (grp << s) + k;
            int p1  = p0 + half;
            double2 w  = tw[k << tshift];
            double2 uu = a[p0];
            double2 v  = a[p1];
            double vr = v.x * w.x - v.y * w.y;
            double vi = v.x * w.y + v.y * w.x;
            a[p0] = make_double2(uu.x + vr, uu.y + vi);
            a[p1] = make_double2(uu.x - vr, uu.y - vi);
        }
        __syncthreads();
    }

    // unpack: X_k = (Z_k + conj(Z_{N-k}))/2 ; Y_k = (Z_k - conj(Z_{N-k}))/(2i)
    for (int k = tid; k < FB; k += 128) {
        int m = (LN - k) & (LN - 1);
        double2 zk = a[k];
        double2 zm = a[m];
        double xr = 0.5 * (zk.x + zm.x);
        double xi = 0.5 * (zk.y - zm.y);
        double yr = 0.5 * (zk.y + zm.y);
        double yi = 0.5 * (zm.x - zk.x);
        double m0 = sqrt(xr * xr + xi * xi);
        double m1 = sqrt(yr * yr + yi * yi);
        // transposed store: rows r0, r0+1 are adjacent -> one double2
        *(double2*)&xft[(size_t)k * NROW + r0] = make_double2(m0, m1);
    }
}

// ---------------------------------------------------------------------------
// Kernel 2: Zt[b][g][i] = sum_f xft[f][row] * At_d[f][g], 8 rows per block.
// 256 blocks x 320 threads (thread = g, active g<257).
// xft reads are wave-uniform -> scalar loads (SGPR); At_d coalesced vmem.
// Per f per wave: 1 s_load_dwordx16 + 1 global_load_dwordx2 + 8 v_fmac_f64.
// ---------------------------------------------------------------------------
__global__ __launch_bounds__(320)
void k_zmat(const double* __restrict__ xft,
            const double* __restrict__ At_d,
            double* __restrict__ Zt) {
    const int r0 = blockIdx.x * 8;          // row base (same b for all 8)
    const int t  = threadIdx.x;             // 0..319, active t<257
    if (t >= FB) return;
    const int g = t;

    double acc[8];
    #pragma unroll
    for (int r = 0; r < 8; ++r) acc[r] = 0.0;

    #pragma unroll 2
    for (int f = 0; f < FB; ++f) {
        const double* xr = xft + (size_t)f * NROW + r0;  // uniform address
        double av = At_d[(size_t)f * FB + g];            // coalesced
        #pragma unroll
        for (int r = 0; r < 8; ++r) acc[r] += xr[r] * av;
    }

    const int b  = r0 >> 7;
    const int i0 = r0 & (CB - 1);
    double* zp = Zt + ((size_t)b * FB + g) * CB + i0;
    #pragma unroll
    for (int r = 0; r < 4; ++r)
        *(double2*)&zp[2 * r] = make_double2(acc[2 * r], acc[2 * r + 1]);
}

// ---------------------------------------------------------------------------
// Kernel 3a: partial distances, strided-slot 8x4 micro-tile.
// Grid: 16 b x 2 ti x 8 chunks = 256 blocks, 256 threads.
// Block tile: 64(i) x 128(j) over one g-chunk (32 or 33 g).
// Thread (it=tid>>5, jt=tid&31): i-slots {i0+it+8s}, j-slots {jt+32q}.
// All LDS reads conflict-free (broadcast or unit-stride b64).
// ---------------------------------------------------------------------------
__global__ __launch_bounds__(256)
void k_dist(const double* __restrict__ Zt, double* __restrict__ distp) {
    __shared__ double si[33][64];
    __shared__ double sj[33][128];
    const int blk = blockIdx.x;
    const int c   = blk & 7;
    const int ti  = (blk >> 3) & 1;
    const int b   = blk >> 4;
    const int g0  = c * 32;
    const int gn  = (c == 7) ? 33 : 32;
    const int i0  = ti * 64;
    const double* Zb = Zt + (size_t)b * FB * CB;
    const int tid = threadIdx.x;

    for (int idx = tid; idx < gn * 64; idx += 256) {
        int gg = idx >> 6, ii = idx & 63;
        si[gg][ii] = Zb[(size_t)(g0 + gg) * CB + i0 + ii];
    }
    for (int idx = tid; idx < gn * 128; idx += 256) {
        int gg = idx >> 7, jj = idx & 127;
        sj[gg][jj] = Zb[(size_t)(g0 + gg) * CB + jj];
    }
    __syncthreads();

    const int it = tid >> 5;     // 0..7
    const int jt = tid & 31;     // 0..31

    double acc[8][4];
    #pragma unroll
    for (int s = 0; s < 8; ++s)
        #pragma unroll
        for (int q = 0; q < 4; ++q) acc[s][q] = 0.0;

    for (int gg = 0; gg < gn; ++gg) {
        double av[8], bv[4];
        #pragma unroll
        for (int s = 0; s < 8; ++s) av[s] = si[gg][it + 8 * s];
        #pragma unroll
        for (int q = 0; q < 4; ++q) bv[q] = sj[gg][jt + 32 * q];
        #pragma unroll
        for (int s = 0; s < 8; ++s)
            #pragma unroll
            for (int q = 0; q < 4; ++q) {
                double e = av[s] - bv[q];
                acc[s][q] += e * e;
            }
    }

    double* dpb = distp + (((size_t)c * 16 + b) * CB + i0 + it) * CB + jt;
    #pragma unroll
    for (int s = 0; s < 8; ++s)
        #pragma unroll
        for (int q = 0; q < 4; ++q)
            dpb[(size_t)(8 * s) * CB + 32 * q] = acc[s][q];
}

// ---------------------------------------------------------------------------
// Kernel 3b: combine partials, rowmax, logits, gumbel compare -> mask.
// ---------------------------------------------------------------------------
__global__ __launch_bounds__(128)
void k_mask2(const double* __restrict__ distp,
             const float* __restrict__ gu,
             float* __restrict__ out) {
    __shared__ double wmax[2];
    const int bi = blockIdx.x;       // b*128 + i
    const int i  = bi & (CB - 1);
    const int b  = bi >> 7;
    const int j  = threadIdx.x;      // 0..127

    const size_t sc   = (size_t)16 * CB * CB;
    const size_t base = ((size_t)b * CB + i) * CB + j;
    double s = 0.0;
    #pragma unroll
    for (int c = 0; c < GC; ++c) s += distp[base + (size_t)c * sc];

    double ed = 1.0 / (s + 3e-8);
    if (j == i) ed = 0.0;            // * (1 - eye)

    double m = ed;
    #pragma unroll
    for (int off = 32; off >= 1; off >>= 1)
        m = fmax(m, __shfl_xor(m, off, 64));
    if ((j & 63) == 0) wmax[j >> 6] = m;
    __syncthreads();
    double emax = fmax(wmax[0], wmax[1]);

    double p = ed / (emax + 1e-8);
    if (j == i) p = p + 1.0;         // + eye
    p *= 0.99;
    double logits = log(p + 1e-8) - log((1.0 - p) + 1e-8);

    float2 u2 = ((const float2*)gu)[(size_t)bi * CB + j];
    double g0 = -log(-log((double)u2.x + 1e-20) + 1e-20);
    double g1 = -log(-log((double)u2.y + 1e-20) + 1e-20);

    out[(size_t)bi * CB + j] = (logits + g0 >= -logits + g1) ? 1.0f : 0.0f;
}

// ---------------------------------------------------------------------------
extern "C" void kernel_launch(void* const* d_in, const int* in_sizes, int n_in,
                              void* d_out, int out_size, void* d_ws, size_t ws_size,
                              hipStream_t stream) {
    const float* x  = (const float*)d_in[0];   // (16,128,512)
    const float* A  = (const float*)d_in[1];   // (257,257)
    const float* gu = (const float*)d_in[2];   // (16,128,128,2)
    float* out = (float*)d_out;                // (16,1,128,128)

    char* ws = (char*)d_ws;
    size_t o = 0;
    double2* tw  = (double2*)(ws + o); o += 4096;
    double* At_d = (double*)(ws + o);  o += ((size_t)FB * FB * 8 + 511) / 512 * 512; // 528 KB
    double* xft  = (double*)(ws + o);  o += (size_t)FB * NROW * 8;     // 4.21 MB (transposed)
    double* Zt   = (double*)(ws + o);  o += (size_t)16 * FB * CB * 8;  // 4.21 MB
    double* dp   = (double*)(ws + o);  o += (size_t)GC * 16 * CB * CB * 8;  // 16.8 MB

    hipLaunchKernelGGL(k_prep,  dim3(260),      dim3(256), 0, stream, A, At_d, tw);
    hipLaunchKernelGGL(k_fft2,  dim3(NROW / 2), dim3(128), 0, stream, x, tw, xft);
    hipLaunchKernelGGL(k_zmat,  dim3(NROW / 8), dim3(320), 0, stream, xft, At_d, Zt);
    hipLaunchKernelGGL(k_dist,  dim3(256),      dim3(256), 0, stream, Zt, dp);
    hipLaunchKernelGGL(k_mask2, dim3(NROW),     dim3(128), 0, stream, dp, gu, out);
}

// Round 6
// 65.534 us; speedup vs baseline: 1.8835x; 1.8835x over previous
//
#include <hip/hip_runtime.h>

// Problem sizes
#define LN   512      // FFT length
#define FB   257      // rfft bins = L/2+1
#define CB   128      // channels
#define NROW 2048     // B*C rows
#define KP   288      // padded f (zeros)
#define NP   320      // padded g (never read past 256)
#define GC   8        // dist g-chunks (7x32 + 1x33)

// ---------------------------------------------------------------------------
// Kernel 0: prep.  blocks [0,360): At_d[f][g] = A[g][f] (0 outside 257x257)
//                  blocks [360,608): zero xft pad rows f=257..287
//                  block 608: twiddles tw[j] = exp(-2*pi*i*j/512)
// ---------------------------------------------------------------------------
__global__ __launch_bounds__(256)
void k_prep(const float* __restrict__ A, double* __restrict__ At_d,
            double* __restrict__ xft, double2* __restrict__ tw) {
    const int bx = blockIdx.x;
    if (bx < 360) {
        int idx = bx * 256 + threadIdx.x;
        if (idx < KP * NP) {
            int f = idx / NP, g = idx - f * NP;
            At_d[idx] = (f < FB && g < FB) ? (double)A[g * FB + f] : 0.0;
        }
    } else if (bx < 608) {
        int idx = (bx - 360) * 256 + threadIdx.x;
        if (idx < (KP - FB) * NROW)
            xft[(size_t)FB * NROW + idx] = 0.0;
    } else {
        int j = threadIdx.x;  // 0..255
        const double PI = 3.14159265358979323846264338327950288;
        double s, c;
        sincos(-2.0 * PI * (double)j / 512.0, &s, &c);
        tw[j] = make_double2(c, s);
    }
}

// ---------------------------------------------------------------------------
// Kernel 1: paired real FFT — one complex-512 FFT per TWO input rows
// (x_r0 + i*x_r1), radix-2 DIT in LDS, unpack both magnitudes.
// Output TRANSPOSED: xft[f][row].  1024 blocks x 128 threads.  (proven r4/r5)
// ---------------------------------------------------------------------------
__global__ __launch_bounds__(128)
void k_fft2(const float* __restrict__ x,
            const double2* __restrict__ twg,
            double* __restrict__ xft) {
    __shared__ double2 a[LN];
    __shared__ double2 tw[256];
    const int pair = blockIdx.x;          // 0..1023
    const int tid  = threadIdx.x;         // 0..127
    const int r0   = pair * 2;

    for (int t = tid; t < 256; t += 128) tw[t] = twg[t];

    const float* x0 = x + (size_t)r0 * LN;
    const float* x1 = x0 + LN;
    #pragma unroll
    for (int q = 0; q < 4; ++q) {
        int n = tid + 128 * q;
        int r = (int)(__brev((unsigned)n) >> 23);  // 9-bit reverse
        a[r] = make_double2((double)x0[n], (double)x1[n]);
    }
    __syncthreads();

    for (int s = 1; s <= 9; ++s) {
        const int half   = 1 << (s - 1);
        const int tshift = 9 - s;
        #pragma unroll
        for (int u = 0; u < 2; ++u) {
            int t   = tid + 128 * u;
            int k   = t & (half - 1);
            int grp = t >> (s - 1);
            int p0  = (grp << s) + k;
            int p1  = p0 + half;
            double2 w  = tw[k << tshift];
            double2 uu = a[p0];
            double2 v  = a[p1];
            double vr = v.x * w.x - v.y * w.y;
            double vi = v.x * w.y + v.y * w.x;
            a[p0] = make_double2(uu.x + vr, uu.y + vi);
            a[p1] = make_double2(uu.x - vr, uu.y - vi);
        }
        __syncthreads();
    }

    for (int k = tid; k < FB; k += 128) {
        int m = (LN - k) & (LN - 1);
        double2 zk = a[k];
        double2 zm = a[m];
        double xr = 0.5 * (zk.x + zm.x);
        double xi = 0.5 * (zk.y - zm.y);
        double yr = 0.5 * (zk.y + zm.y);
        double yi = 0.5 * (zm.x - zk.x);
        double m0 = sqrt(xr * xr + xi * xi);
        double m1 = sqrt(yr * yr + yi * yi);
        *(double2*)&xft[(size_t)k * NROW + r0] = make_double2(m0, m1);
    }
}

// ---------------------------------------------------------------------------
// Kernel 2: f64 GEMM  C[row][g] = sum_f xft[f][row] * At_d[f][g].
// Tile 64(rows) x 64(g), 256 threads, micro 4x4 (paired slots {2t,2t+1,
// 32+2t,32+2t+1} -> conflict-free double2 LDS reads).  K-split by S
// (runtime): block s covers f in [s*288/S, (s+1)*288/S), staged 24 at a time.
// Output (per split s): out[s][b][g][ch] with b=row>>7, ch=row&127.
// ---------------------------------------------------------------------------
__global__ __launch_bounds__(256)
void k_zmat(const double* __restrict__ xft, const double* __restrict__ At_d,
            double* __restrict__ out, int S) {
    __shared__ double sX[24][64];
    __shared__ double sA[24][64];
    const int bx  = blockIdx.x;
    const int s   = bx % S;
    const int rem = bx / S;
    const int gt  = rem % 5;
    const int rt  = rem / 5;
    const int r0 = rt * 64, g0 = gt * 64;
    const int tid = threadIdx.x;
    const int tx = tid & 15, ty = tid >> 4;
    const int kspan = KP / S;            // 72 (S=4) or 288 (S=1)
    const int nst   = kspan / 24;
    const int f00   = s * kspan;

    double acc[2][2][2][2];
    #pragma unroll
    for (int p = 0; p < 2; ++p)
        #pragma unroll
        for (int w = 0; w < 2; ++w)
            #pragma unroll
            for (int q = 0; q < 2; ++q)
                #pragma unroll
                for (int v = 0; v < 2; ++v) acc[p][w][q][v] = 0.0;

    for (int st = 0; st < nst; ++st) {
        const int f0 = f00 + st * 24;
        __syncthreads();
        #pragma unroll
        for (int q6 = 0; q6 < 6; ++q6) {
            int idx = tid + 256 * q6;
            int kk = idx >> 6, rr = idx & 63;
            sX[kk][rr] = xft[(size_t)(f0 + kk) * NROW + r0 + rr];
            sA[kk][rr] = At_d[(size_t)(f0 + kk) * NP + g0 + rr];
        }
        __syncthreads();
        #pragma unroll 4
        for (int k = 0; k < 24; ++k) {
            double2 xa0 = *(const double2*)&sX[k][2 * ty];
            double2 xa1 = *(const double2*)&sX[k][32 + 2 * ty];
            double2 ab0 = *(const double2*)&sA[k][2 * tx];
            double2 ab1 = *(const double2*)&sA[k][32 + 2 * tx];
            acc[0][0][0][0] += xa0.x * ab0.x;
            acc[0][0][0][1] += xa0.x * ab0.y;
            acc[0][0][1][0] += xa0.x * ab1.x;
            acc[0][0][1][1] += xa0.x * ab1.y;
            acc[0][1][0][0] += xa0.y * ab0.x;
            acc[0][1][0][1] += xa0.y * ab0.y;
            acc[0][1][1][0] += xa0.y * ab1.x;
            acc[0][1][1][1] += xa0.y * ab1.y;
            acc[1][0][0][0] += xa1.x * ab0.x;
            acc[1][0][0][1] += xa1.x * ab0.y;
            acc[1][0][1][0] += xa1.x * ab1.x;
            acc[1][0][1][1] += xa1.x * ab1.y;
            acc[1][1][0][0] += xa1.y * ab0.x;
            acc[1][1][0][1] += xa1.y * ab0.y;
            acc[1][1][1][0] += xa1.y * ab1.x;
            acc[1][1][1][1] += xa1.y * ab1.y;
        }
    }

    const int b   = r0 >> 7;
    const int ch0 = r0 & 127;
    double* op = out + (size_t)s * ((size_t)16 * NP * CB);
    #pragma unroll
    for (int q = 0; q < 2; ++q)
        #pragma unroll
        for (int v = 0; v < 2; ++v) {
            int g = g0 + q * 32 + 2 * tx + v;
            #pragma unroll
            for (int p = 0; p < 2; ++p) {
                int ch = ch0 + p * 32 + 2 * ty;
                *(double2*)&op[((size_t)b * NP + g) * CB + ch] =
                    make_double2(acc[p][0][q][v], acc[p][1][q][v]);
            }
        }
}

// ---------------------------------------------------------------------------
// Kernel 2b: combine the 4 K-split partials: Zt = sum_s Ztp[s].
// 640 blocks x 256 threads, 4 elems/thread, coalesced.
// ---------------------------------------------------------------------------
__global__ __launch_bounds__(256)
void k_comb(const double* __restrict__ Ztp, double* __restrict__ Zt) {
    const size_t stride = (size_t)16 * NP * CB;  // 655360
    size_t base = (size_t)blockIdx.x * 1024 + threadIdx.x;
    #pragma unroll
    for (int k = 0; k < 4; ++k) {
        size_t e = base + (size_t)k * 256;
        Zt[e] = Ztp[e] + Ztp[e + stride] + Ztp[e + 2 * stride] + Ztp[e + 3 * stride];
    }
}

// ---------------------------------------------------------------------------
// Kernel 3a: Gram partials G[c][b][i][j] = sum_{g in chunk c} Z_i[g]*Z_j[g],
// plus per-chunk j-norm partials np[b][c][j] (computed by it==0 blocks).
// Grid: 16 b x 2 it x 2 jt x 8 c = 512 blocks, 256 threads.
// Tile 64(i) x 64(j), micro 4x4 paired-slot double2 reads.
// ---------------------------------------------------------------------------
__global__ __launch_bounds__(256)
void k_dist(const double* __restrict__ Zt, double* __restrict__ dp,
            double* __restrict__ np_) {
    __shared__ double si[33][64];
    __shared__ double sj[33][64];
    const int bx = blockIdx.x;
    const int c  = bx & 7;
    const int jt = (bx >> 3) & 1;
    const int it = (bx >> 4) & 1;
    const int b  = bx >> 5;
    const int g0 = c * 32;
    const int gn = (c == 7) ? 33 : 32;
    const int i0 = it * 64, j0 = jt * 64;
    const int tid = threadIdx.x;
    const double* Zb = Zt + (size_t)b * NP * CB;

    for (int idx = tid; idx < gn * 64; idx += 256) {
        int gg = idx >> 6, ii = idx & 63;
        si[gg][ii] = Zb[(size_t)(g0 + gg) * CB + i0 + ii];
        sj[gg][ii] = Zb[(size_t)(g0 + gg) * CB + j0 + ii];
    }
    __syncthreads();

    // per-chunk j-norm partials (each (b,c,j) written exactly once: it==0)
    if (it == 0 && tid < 64) {
        double na = 0.0;
        for (int gg = 0; gg < gn; ++gg) { double z = sj[gg][tid]; na += z * z; }
        np_[((size_t)b * GC + c) * CB + j0 + tid] = na;
    }

    const int tx = tid & 15, ty = tid >> 4;
    double acc[2][2][2][2];
    #pragma unroll
    for (int p = 0; p < 2; ++p)
        #pragma unroll
        for (int w = 0; w < 2; ++w)
            #pragma unroll
            for (int q = 0; q < 2; ++q)
                #pragma unroll
                for (int v = 0; v < 2; ++v) acc[p][w][q][v] = 0.0;

    #pragma unroll 4
    for (int gg = 0; gg < gn; ++gg) {
        double2 a0 = *(const double2*)&si[gg][2 * ty];
        double2 a1 = *(const double2*)&si[gg][32 + 2 * ty];
        double2 b0 = *(const double2*)&sj[gg][2 * tx];
        double2 b1 = *(const double2*)&sj[gg][32 + 2 * tx];
        acc[0][0][0][0] += a0.x * b0.x;
        acc[0][0][0][1] += a0.x * b0.y;
        acc[0][0][1][0] += a0.x * b1.x;
        acc[0][0][1][1] += a0.x * b1.y;
        acc[0][1][0][0] += a0.y * b0.x;
        acc[0][1][0][1] += a0.y * b0.y;
        acc[0][1][1][0] += a0.y * b1.x;
        acc[0][1][1][1] += a0.y * b1.y;
        acc[1][0][0][0] += a1.x * b0.x;
        acc[1][0][0][1] += a1.x * b0.y;
        acc[1][0][1][0] += a1.x * b1.x;
        acc[1][0][1][1] += a1.x * b1.y;
        acc[1][1][0][0] += a1.y * b0.x;
        acc[1][1][0][1] += a1.y * b0.y;
        acc[1][1][1][0] += a1.y * b1.x;
        acc[1][1][1][1] += a1.y * b1.y;
    }

    double* outp = dp + ((size_t)c * 16 + b) * CB * CB;
    #pragma unroll
    for (int p = 0; p < 2; ++p)
        #pragma unroll
        for (int w = 0; w < 2; ++w) {
            int row = i0 + p * 32 + 2 * ty + w;
            #pragma unroll
            for (int q = 0; q < 2; ++q)
                *(double2*)&outp[(size_t)row * CB + j0 + q * 32 + 2 * tx] =
                    make_double2(acc[p][w][q][0], acc[p][w][q][1]);
        }
}

// ---------------------------------------------------------------------------
// Kernel 3b: dist = n_i + n_j - 2G, rowmax, logits (ratio-log), gumbel
// compare -> binary mask.  2048 blocks x 128 threads.
// ---------------------------------------------------------------------------
__global__ __launch_bounds__(128)
void k_mask2(const double* __restrict__ dp, const double* __restrict__ np_,
             const float* __restrict__ gu, float* __restrict__ out) {
    __shared__ double sn[CB];
    __shared__ double wmax[2];
    const int bi = blockIdx.x;       // b*128 + i
    const int i  = bi & (CB - 1);
    const int b  = bi >> 7;
    const int j  = threadIdx.x;      // 0..127

    double G = 0.0, nj = 0.0;
    #pragma unroll
    for (int c = 0; c < GC; ++c) {
        G  += dp[(((size_t)c * 16 + b) * CB + i) * CB + j];
        nj += np_[((size_t)b * GC + c) * CB + j];
    }
    sn[j] = nj;
    __syncthreads();
    double ni = sn[i];
    double dist = ni + nj - 2.0 * G;

    double ed = 1.0 / (dist + 3e-8);
    if (j == i) ed = 0.0;            // * (1 - eye)

    double m = ed;
    #pragma unroll
    for (int off = 32; off >= 1; off >>= 1)
        m = fmax(m, __shfl_xor(m, off, 64));
    if ((j & 63) == 0) wmax[j >> 6] = m;
    __syncthreads();
    double emax = fmax(wmax[0], wmax[1]);

    double p = ed / (emax + 1e-8);
    if (j == i) p += 1.0;            // + eye
    p *= 0.99;
    double L = log((p + 1e-8) / (1.0 - p + 1e-8));

    float2 u2 = ((const float2*)gu)[(size_t)bi * CB + j];
    double w0 = -log((double)u2.x + 1e-20);
    double w1 = -log((double)u2.y + 1e-20);
    double R = log((w0 + 1e-20) / (w1 + 1e-20));

    // a0 - a1 = 2*logits + g0 - g1 = 2L - R ; tie -> index 0 -> 1
    out[(size_t)bi * CB + j] = (2.0 * L >= R) ? 1.0f : 0.0f;
}

// ---------------------------------------------------------------------------
extern "C" void kernel_launch(void* const* d_in, const int* in_sizes, int n_in,
                              void* d_out, int out_size, void* d_ws, size_t ws_size,
                              hipStream_t stream) {
    const float* x  = (const float*)d_in[0];   // (16,128,512)
    const float* A  = (const float*)d_in[1];   // (257,257)
    const float* gu = (const float*)d_in[2];   // (16,128,128,2)
    float* out = (float*)d_out;                // (16,1,128,128)

    char* base = (char*)d_ws;
    const size_t szAt  = (size_t)KP * NP * 8;          //   737,280
    const size_t szXft = (size_t)KP * NROW * 8;        // 4,718,592
    const size_t szZtp = (size_t)4 * 16 * NP * CB * 8; // 20,971,520
    const size_t szZt  = (size_t)16 * NP * CB * 8;     // 5,242,880
    const size_t szDp  = (size_t)GC * 16 * CB * CB * 8;// 16,777,216
    const size_t szNp  = (size_t)16 * GC * CB * 8;     //   131,072

    double *At_d, *xft, *Ztp, *dp, *Zt, *np, *zout;
    double2* tw;
    int S;
    const size_t regionA   = szAt + szXft + szZtp;     // dp aliases this (dead by dist)
    const size_t need_fast = regionA + szZt + szNp + 4096;

    if (ws_size >= need_fast) {
        S = 4;
        At_d = (double*)base;
        xft  = (double*)(base + szAt);
        Ztp  = (double*)(base + szAt + szXft);
        dp   = (double*)base;                          // alias: At/xft/Ztp dead
        Zt   = (double*)(base + regionA);
        np   = (double*)(base + regionA + szZt);
        tw   = (double2*)(base + regionA + szZt + szNp);
        zout = Ztp;
    } else {
        S = 1;
        dp   = (double*)base;
        At_d = (double*)base;                          // inside dp, dead by dist
        xft  = (double*)(base + szAt);
        Zt   = (double*)(base + szDp);
        np   = (double*)(base + szDp + szZt);
        tw   = (double2*)(base + szDp + szZt + szNp);
        zout = Zt;
    }

    hipLaunchKernelGGL(k_prep,  dim3(609),      dim3(256), 0, stream, A, At_d, xft, tw);
    hipLaunchKernelGGL(k_fft2,  dim3(NROW / 2), dim3(128), 0, stream, x, tw, xft);
    hipLaunchKernelGGL(k_zmat,  dim3(160 * S),  dim3(256), 0, stream, xft, At_d, zout, S);
    if (S == 4)
        hipLaunchKernelGGL(k_comb, dim3(640),   dim3(256), 0, stream, Ztp, Zt);
    hipLaunchKernelGGL(k_dist,  dim3(512),      dim3(256), 0, stream, Zt, dp, np);
    hipLaunchKernelGGL(k_mask2, dim3(NROW),     dim3(128), 0, stream, dp, np, gu, out);
}

// Round 8
// 50.799 us; speedup vs baseline: 2.4299x; 1.2901x over previous
//
#include <hip/hip_runtime.h>

// Problem sizes
#define LN   512      // FFT length
#define FB   257      // rfft bins = L/2+1
#define CB   128      // channels
#define NROW 2048     // B*C rows
#define KF   260      // padded f (65 * 4) for mfma K-loop
#define NP   272      // padded g (17 * 16) — At cols & Zt rows
#define GC   8        // dist g-chunks (7x32 + 1x33)

typedef double double4_t __attribute__((ext_vector_type(4)));

// ---------------------------------------------------------------------------
// Kernel 0: prep.  blocks [0,277): At_d[f][g] = A[g][f] (0 outside 257x257)
//                  blocks [277,301): zero xft pad rows f=257..259
//                  block 301: twiddles tw[j] = exp(-2*pi*i*j/512) (direct)
// ---------------------------------------------------------------------------
__global__ __launch_bounds__(256)
void k_prep(const float* __restrict__ A, double* __restrict__ At_d,
            double* __restrict__ xft, double2* __restrict__ tw) {
    const int bx = blockIdx.x;
    if (bx < 277) {
        int idx = bx * 256 + threadIdx.x;
        if (idx < KF * NP) {
            int f = idx / NP, g = idx - f * NP;
            At_d[idx] = (f < FB && g < FB) ? (double)A[g * FB + f] : 0.0;
        }
    } else if (bx < 301) {
        int idx = (bx - 277) * 256 + threadIdx.x;   // 24*256 = 6144 = 3*2048
        xft[(size_t)FB * NROW + idx] = 0.0;
    } else {
        int j = threadIdx.x;  // 0..255
        const double PI = 3.14159265358979323846264338327950288;
        double s, c;
        sincos(-2.0 * PI * (double)j / 512.0, &s, &c);
        tw[j] = make_double2(c, s);
    }
}

// ---------------------------------------------------------------------------
// Kernel 1: paired real FFT — one complex-512 FFT per TWO input rows
// (x_r0 + i*x_r1), radix-2 DIT in LDS, unpack both magnitudes.
// Output TRANSPOSED: xft[f][row].  1024 blocks x 128 threads.  (r6 verbatim)
// ---------------------------------------------------------------------------
__global__ __launch_bounds__(128)
void k_fft2(const float* __restrict__ x,
            const double2* __restrict__ twg,
            double* __restrict__ xft) {
    __shared__ double2 a[LN];
    __shared__ double2 tw[256];
    const int pair = blockIdx.x;          // 0..1023
    const int tid  = threadIdx.x;         // 0..127
    const int r0   = pair * 2;

    for (int t = tid; t < 256; t += 128) tw[t] = twg[t];

    const float* x0 = x + (size_t)r0 * LN;
    const float* x1 = x0 + LN;
    #pragma unroll
    for (int q = 0; q < 4; ++q) {
        int n = tid + 128 * q;
        int r = (int)(__brev((unsigned)n) >> 23);  // 9-bit reverse
        a[r] = make_double2((double)x0[n], (double)x1[n]);
    }
    __syncthreads();

    for (int s = 1; s <= 9; ++s) {
        const int half   = 1 << (s - 1);
        const int tshift = 9 - s;
        #pragma unroll
        for (int u = 0; u < 2; ++u) {
            int t   = tid + 128 * u;
            int k   = t & (half - 1);
            int grp = t >> (s - 1);
            int p0  = (grp << s) + k;
            int p1  = p0 + half;
            double2 w  = tw[k << tshift];
            double2 uu = a[p0];
            double2 v  = a[p1];
            double vr = v.x * w.x - v.y * w.y;
            double vi = v.x * w.y + v.y * w.x;
            a[p0] = make_double2(uu.x + vr, uu.y + vi);
            a[p1] = make_double2(uu.x - vr, uu.y - vi);
        }
        __syncthreads();
    }

    for (int k = tid; k < FB; k += 128) {
        int m = (LN - k) & (LN - 1);
        double2 zk = a[k];
        double2 zm = a[m];
        double xr = 0.5 * (zk.x + zm.x);
        double xi = 0.5 * (zk.y - zm.y);
        double yr = 0.5 * (zk.y + zm.y);
        double yi = 0.5 * (zm.x - zk.x);
        double m0 = sqrt(xr * xr + xi * xi);
        double m1 = sqrt(yr * yr + yi * yi);
        *(double2*)&xft[(size_t)k * NROW + r0] = make_double2(m0, m1);
    }
}

// ---------------------------------------------------------------------------
// Kernel 2 (THE ONE CHANGE vs r6): Zt[b][g][ch] = sum_f At_d[f][g] *
// xft[f][b*128+ch] via v_mfma_f64_16x16x4.  Wave-tile 16g x 16ch, K=260
// (65 mfma), depth-2 prefetch, NO LDS.  544 blocks x 256 threads
// (4 waves: same g-tile, 4 consecutive ch-tiles).
// A-frag: lane holds At_d[f0 + (l>>4)][g0 + (l&15)]   (M=g, K=f)
// B-frag: lane holds xft [f0 + (l>>4)][ch0 + (l&15)]  (K=f, N=ch)
// D: row(g) = 4*(l>>4)+r, col(ch) = l&15   (AMD sample layout)
// ---------------------------------------------------------------------------
__global__ __launch_bounds__(256)
void k_zmat(const double* __restrict__ xft, const double* __restrict__ At_d,
            double* __restrict__ Zt) {
    const int bx  = blockIdx.x;
    const int tid = threadIdx.x;
    const int w   = tid >> 6;
    const int l   = tid & 63;
    const int q   = l >> 4;       // k-slot 0..3
    const int m   = l & 15;

    const int gt  = bx % 17;
    const int cht = (bx / 17) * 4 + w;   // 0..127
    const int g0  = gt * 16;
    const int ch0 = cht * 16;

    const double* pa = At_d + (size_t)q * NP + g0 + m;
    const double* pb = xft + (size_t)q * NROW + ch0 + m;

    double4_t acc = {0.0, 0.0, 0.0, 0.0};
    double a0 = pa[0],              b0 = pb[0];
    double a1 = pa[(size_t)4 * NP], b1 = pb[(size_t)4 * NROW];
    for (int it = 0; it < 63; ++it) {
        double a2 = pa[(size_t)(it + 2) * 4 * NP];
        double b2 = pb[(size_t)(it + 2) * 4 * NROW];
        acc = __builtin_amdgcn_mfma_f64_16x16x4f64(a0, b0, acc, 0, 0, 0);
        a0 = a1; a1 = a2; b0 = b1; b1 = b2;
    }
    acc = __builtin_amdgcn_mfma_f64_16x16x4f64(a0, b0, acc, 0, 0, 0);
    acc = __builtin_amdgcn_mfma_f64_16x16x4f64(a1, b1, acc, 0, 0, 0);

    const int b   = cht >> 3;
    const int chL = ((cht & 7) << 4) + m;
    double* zp = Zt + ((size_t)b * NP + g0 + 4 * q) * CB + chL;
    #pragma unroll
    for (int r = 0; r < 4; ++r) zp[(size_t)r * CB] = acc[r];
}

// ---------------------------------------------------------------------------
// Kernel 3a: Gram partials (r6 verbatim, vector path).
// G[c][b][i][j] = sum_{g in chunk c} Z_i[g]*Z_j[g] + per-chunk j-norms.
// Grid: 16 b x 2 it x 2 jt x 8 c = 512 blocks, 256 threads.
// ---------------------------------------------------------------------------
__global__ __launch_bounds__(256)
void k_dist(const double* __restrict__ Zt, double* __restrict__ dp,
            double* __restrict__ np_) {
    __shared__ double si[33][64];
    __shared__ double sj[33][64];
    const int bx = blockIdx.x;
    const int c  = bx & 7;
    const int jt = (bx >> 3) & 1;
    const int it = (bx >> 4) & 1;
    const int b  = bx >> 5;
    const int g0 = c * 32;
    const int gn = (c == 7) ? 33 : 32;
    const int i0 = it * 64, j0 = jt * 64;
    const int tid = threadIdx.x;
    const double* Zb = Zt + (size_t)b * NP * CB;

    for (int idx = tid; idx < gn * 64; idx += 256) {
        int gg = idx >> 6, ii = idx & 63;
        si[gg][ii] = Zb[(size_t)(g0 + gg) * CB + i0 + ii];
        sj[gg][ii] = Zb[(size_t)(g0 + gg) * CB + j0 + ii];
    }
    __syncthreads();

    if (it == 0 && tid < 64) {
        double na = 0.0;
        for (int gg = 0; gg < gn; ++gg) { double z = sj[gg][tid]; na += z * z; }
        np_[((size_t)b * GC + c) * CB + j0 + tid] = na;
    }

    const int tx = tid & 15, ty = tid >> 4;
    double acc[2][2][2][2];
    #pragma unroll
    for (int p = 0; p < 2; ++p)
        #pragma unroll
        for (int w = 0; w < 2; ++w)
            #pragma unroll
            for (int q = 0; q < 2; ++q)
                #pragma unroll
                for (int v = 0; v < 2; ++v) acc[p][w][q][v] = 0.0;

    #pragma unroll 4
    for (int gg = 0; gg < gn; ++gg) {
        double2 a0 = *(const double2*)&si[gg][2 * ty];
        double2 a1 = *(const double2*)&si[gg][32 + 2 * ty];
        double2 b0 = *(const double2*)&sj[gg][2 * tx];
        double2 b1 = *(const double2*)&sj[gg][32 + 2 * tx];
        acc[0][0][0][0] += a0.x * b0.x;
        acc[0][0][0][1] += a0.x * b0.y;
        acc[0][0][1][0] += a0.x * b1.x;
        acc[0][0][1][1] += a0.x * b1.y;
        acc[0][1][0][0] += a0.y * b0.x;
        acc[0][1][0][1] += a0.y * b0.y;
        acc[0][1][1][0] += a0.y * b1.x;
        acc[0][1][1][1] += a0.y * b1.y;
        acc[1][0][0][0] += a1.x * b0.x;
        acc[1][0][0][1] += a1.x * b0.y;
        acc[1][0][1][0] += a1.x * b1.x;
        acc[1][0][1][1] += a1.x * b1.y;
        acc[1][1][0][0] += a1.y * b0.x;
        acc[1][1][0][1] += a1.y * b0.y;
        acc[1][1][1][0] += a1.y * b1.x;
        acc[1][1][1][1] += a1.y * b1.y;
    }

    double* outp = dp + ((size_t)c * 16 + b) * CB * CB;
    #pragma unroll
    for (int p = 0; p < 2; ++p)
        #pragma unroll
        for (int w = 0; w < 2; ++w) {
            int row = i0 + p * 32 + 2 * ty + w;
            #pragma unroll
            for (int q = 0; q < 2; ++q)
                *(double2*)&outp[(size_t)row * CB + j0 + q * 32 + 2 * tx] =
                    make_double2(acc[p][w][q][0], acc[p][w][q][1]);
        }
}

// ---------------------------------------------------------------------------
// Kernel 3b: dist = n_i + n_j - 2G, rowmax, logits (ratio-log), gumbel
// compare -> binary mask.  (r6 verbatim)  2048 blocks x 128 threads.
// ---------------------------------------------------------------------------
__global__ __launch_bounds__(128)
void k_mask2(const double* __restrict__ dp, const double* __restrict__ np_,
             const float* __restrict__ gu, float* __restrict__ out) {
    __shared__ double sn[CB];
    __shared__ double wmax[2];
    const int bi = blockIdx.x;       // b*128 + i
    const int i  = bi & (CB - 1);
    const int b  = bi >> 7;
    const int j  = threadIdx.x;      // 0..127

    double G = 0.0, nj = 0.0;
    #pragma unroll
    for (int c = 0; c < GC; ++c) {
        G  += dp[(((size_t)c * 16 + b) * CB + i) * CB + j];
        nj += np_[((size_t)b * GC + c) * CB + j];
    }
    sn[j] = nj;
    __syncthreads();
    double ni = sn[i];
    double dist = ni + nj - 2.0 * G;

    double ed = 1.0 / (dist + 3e-8);
    if (j == i) ed = 0.0;            // * (1 - eye)

    double m = ed;
    #pragma unroll
    for (int off = 32; off >= 1; off >>= 1)
        m = fmax(m, __shfl_xor(m, off, 64));
    if ((j & 63) == 0) wmax[j >> 6] = m;
    __syncthreads();
    double emax = fmax(wmax[0], wmax[1]);

    double p = ed / (emax + 1e-8);
    if (j == i) p += 1.0;            // + eye
    p *= 0.99;
    double L = log((p + 1e-8) / (1.0 - p + 1e-8));

    float2 u2 = ((const float2*)gu)[(size_t)bi * CB + j];
    double w0 = -log((double)u2.x + 1e-20);
    double w1 = -log((double)u2.y + 1e-20);
    double R = log((w0 + 1e-20) / (w1 + 1e-20));

    // a0 - a1 = 2*logits + g0 - g1 = 2L - R ; tie -> index 0 -> 1
    out[(size_t)bi * CB + j] = (2.0 * L >= R) ? 1.0f : 0.0f;
}

// ---------------------------------------------------------------------------
extern "C" void kernel_launch(void* const* d_in, const int* in_sizes, int n_in,
                              void* d_out, int out_size, void* d_ws, size_t ws_size,
                              hipStream_t stream) {
    const float* x  = (const float*)d_in[0];   // (16,128,512)
    const float* A  = (const float*)d_in[1];   // (257,257)
    const float* gu = (const float*)d_in[2];   // (16,128,128,2)
    float* out = (float*)d_out;                // (16,1,128,128)

    char* base = (char*)d_ws;
    const size_t szTw  = 4096;
    const size_t szAt  = (size_t)KF * NP * 8;        //   565,760
    const size_t szXft = (size_t)KF * NROW * 8;      // 4,259,840
    const size_t szZt  = (size_t)16 * NP * CB * 8;   // 4,456,448
    const size_t szDp  = (size_t)GC * 16 * CB * CB * 8; // 16,777,216

    double2* tw   = (double2*)base;
    double* At_d  = (double*)(base + szTw);
    double* xft   = (double*)(base + szTw + szAt);
    double* Zt    = (double*)(base + szTw + szAt + szXft);
    double* dp    = (double*)(base + szTw + szAt + szXft + szZt);
    double* np    = (double*)(base + szTw + szAt + szXft + szZt + szDp);

    hipLaunchKernelGGL(k_prep,  dim3(302),      dim3(256), 0, stream, A, At_d, xft, tw);
    hipLaunchKernelGGL(k_fft2,  dim3(NROW / 2), dim3(128), 0, stream, x, tw, xft);
    hipLaunchKernelGGL(k_zmat,  dim3(544),      dim3(256), 0, stream, xft, At_d, Zt);
    hipLaunchKernelGGL(k_dist,  dim3(512),      dim3(256), 0, stream, Zt, dp, np);
    hipLaunchKernelGGL(k_mask2, dim3(NROW),     dim3(128), 0, stream, dp, np, gu, out);
}